// Round 4
// baseline (504.318 us; speedup 1.0000x reference)
//
#include <hip/hip_runtime.h>
#include <hip/hip_bf16.h>
#include <math.h>
#include <stdint.h>

#define H     256
#define K2    512
#define SDEC  2048
#define LCSH  14
#define BM    64
#define NTHR  256

typedef __attribute__((ext_vector_type(8))) short  short8;
typedef __attribute__((ext_vector_type(4))) float  f32x4;

__device__ __forceinline__ unsigned short f2bf(float f) {
  union { float f; unsigned int u; } c; c.f = f;
  unsigned int u = c.u;
  unsigned int r = u + 0x7fffu + ((u >> 16) & 1u);   // RNE
  return (unsigned short)(r >> 16);
}

// Blocks 0..31: fused weight tiles (wft = W1*W2_bot + W2_top, transposed, bf16).
// Block 32: fused bias (biasf = b2 + b1*W2_bot) with 16 loads in flight.
__global__ __launch_bounds__(256) void fuse_weights(
    const float* __restrict__ W1, const float* __restrict__ W2,
    const float* __restrict__ b1, const float* __restrict__ b2,
    unsigned short* __restrict__ wft, float* __restrict__ biasf) {
  if (blockIdx.x == 32) {
    const int n = threadIdx.x;
    float a0 = b2[n], a1 = 0.f, a2 = 0.f, a3 = 0.f;
#pragma unroll 4
    for (int j = 0; j < H; j += 4) {
      a0 += b1[j + 0] * W2[(size_t)(H + j + 0) * H + n];
      a1 += b1[j + 1] * W2[(size_t)(H + j + 1) * H + n];
      a2 += b1[j + 2] * W2[(size_t)(H + j + 2) * H + n];
      a3 += b1[j + 3] * W2[(size_t)(H + j + 3) * H + n];
    }
    biasf[n] = (a0 + a1) + (a2 + a3);
    return;
  }

  __shared__ float As[64][65];
  __shared__ float Bs[64][65];
  const int t  = threadIdx.x;
  const int k0 = (blockIdx.x >> 2) * 64;
  const int n0 = (blockIdx.x & 3) * 64;
  const int lr = t >> 2;
  const int ls = t & 3;
  const int tk = t >> 4;
  const int tn = t & 15;

  float acc[4][4];
#pragma unroll
  for (int i = 0; i < 4; ++i)
#pragma unroll
    for (int c = 0; c < 4; ++c) acc[i][c] = 0.0f;

  for (int jt = 0; jt < 4; ++jt) {
    const int j0 = jt * 64;
    __syncthreads();
    const float* a_src = W1 + (size_t)(k0 + lr) * H + j0 + ls * 16;
    const float* b_src = W2 + (size_t)(H + j0 + lr) * H + n0 + ls * 16;
#pragma unroll
    for (int i = 0; i < 16; ++i) {
      As[lr][ls * 16 + i] = a_src[i];
      Bs[lr][ls * 16 + i] = b_src[i];
    }
    __syncthreads();
#pragma unroll 8
    for (int j = 0; j < 64; ++j) {
      float a[4], b[4];
#pragma unroll
      for (int i = 0; i < 4; ++i) a[i] = As[tk * 4 + i][j];
#pragma unroll
      for (int c = 0; c < 4; ++c) b[c] = Bs[j][tn * 4 + c];
#pragma unroll
      for (int i = 0; i < 4; ++i)
#pragma unroll
        for (int c = 0; c < 4; ++c) acc[i][c] += a[i] * b[c];
    }
  }

#pragma unroll
  for (int i = 0; i < 4; ++i) {
    const int k = k0 + tk * 4 + i;
#pragma unroll
    for (int c = 0; c < 4; ++c) {
      const int n = n0 + tn * 4 + c;
      float v = acc[i][c];
      if (k < H) v += W2[(size_t)k * H + n];
      wft[(size_t)n * K2 + k] = f2bf(v);
    }
  }
}

// R3/R4: barrier-free main kernel. __syncthreads drains vmcnt(0) every
// K-step (that drain was the 75% stall), so: m-split waves (wave w owns
// rows w*16..+15, all 256 cols), A loaded per-lane DIRECTLY in MFMA
// fragment layout (lane l: A[row=l&15][k=(l>>4)*8..+7], 32 contiguous
// bytes), B frags from L1/L2-resident wft. Zero LDS, zero barriers; LN
// stats stay inside one 16-lane shfl group; epilogue uses scalar 4B I/O
// (64B-coalesced per 16-lane group). Waves free-run and self-hide latency.
__global__ __launch_bounds__(NTHR, 3) void syl_main(
    const float* __restrict__ cemb, const int* __restrict__ tal,
    const float* __restrict__ dec, const unsigned short* __restrict__ wft,
    const float* __restrict__ biasf, const float* __restrict__ gamma,
    const float* __restrict__ beta, float* __restrict__ out) {

  const int t    = threadIdx.x;
  const int wave = t >> 6;
  const int lane = t & 63;
  const int q    = lane >> 4;
  const int l15  = lane & 15;

  // XCD-chunked swizzle: one batch per XCD -> its 2 MB dec slice stays in
  // that XCD's L2 for the gather.
  const int nwg  = gridDim.x;
  const int bid  = ((nwg & 7) == 0)
                     ? (int)((blockIdx.x & 7) * (nwg >> 3) + (blockIdx.x >> 3))
                     : (int)blockIdx.x;
  const int row0 = bid * BM;
  const int bidx = row0 >> LCSH;

  // this lane's A row (for operand loads)
  const int arow = row0 + wave * 16 + l15;
  int ix = tal[arow];
  const float msk = (ix < 0) ? 0.0f : 1.0f;
  ix = ix < 0 ? 0 : (ix >= SDEC ? SDEC - 1 : ix);

  const float* __restrict__ ap = cemb + (size_t)arow * H + q * 8;
  const float* __restrict__ dp = dec + ((size_t)bidx * SDEC + ix) * H + q * 8;
  const unsigned short* __restrict__ wp = wft + (size_t)l15 * K2 + q * 8;

  f32x4 acc[16];
#pragma unroll
  for (int n = 0; n < 16; ++n) acc[n] = (f32x4){0.f, 0.f, 0.f, 0.f};

  // ---- K-loop, char half (k = 0..255), kk steps of 32 ----
#pragma unroll 2
  for (int kk = 0; kk < 8; ++kk) {
    const float4 a0 = *(const float4*)(ap + kk * 32);
    const float4 a1 = *(const float4*)(ap + kk * 32 + 4);
    unsigned short hb[8];
    hb[0] = f2bf(a0.x); hb[1] = f2bf(a0.y); hb[2] = f2bf(a0.z); hb[3] = f2bf(a0.w);
    hb[4] = f2bf(a1.x); hb[5] = f2bf(a1.y); hb[6] = f2bf(a1.z); hb[7] = f2bf(a1.w);
    const short8 af = *(const short8*)hb;
#pragma unroll
    for (int h = 0; h < 2; ++h) {
      short8 bf[8];
#pragma unroll
      for (int n = 0; n < 8; ++n)
        bf[n] = *(const short8*)(wp + (size_t)((h * 8 + n) * 16) * K2 + kk * 32);
#pragma unroll
      for (int n = 0; n < 8; ++n)
        acc[h * 8 + n] = __builtin_amdgcn_mfma_f32_16x16x32_bf16(
            af, bf[n], acc[h * 8 + n], 0, 0, 0);
    }
  }

  // ---- K-loop, gathered-decoder half (k = 256..511) ----
#pragma unroll 2
  for (int kk = 0; kk < 8; ++kk) {
    float4 a0 = *(const float4*)(dp + kk * 32);
    float4 a1 = *(const float4*)(dp + kk * 32 + 4);
    a0.x *= msk; a0.y *= msk; a0.z *= msk; a0.w *= msk;
    a1.x *= msk; a1.y *= msk; a1.z *= msk; a1.w *= msk;
    unsigned short hb[8];
    hb[0] = f2bf(a0.x); hb[1] = f2bf(a0.y); hb[2] = f2bf(a0.z); hb[3] = f2bf(a0.w);
    hb[4] = f2bf(a1.x); hb[5] = f2bf(a1.y); hb[6] = f2bf(a1.z); hb[7] = f2bf(a1.w);
    const short8 af = *(const short8*)hb;
#pragma unroll
    for (int h = 0; h < 2; ++h) {
      short8 bf[8];
#pragma unroll
      for (int n = 0; n < 8; ++n)
        bf[n] = *(const short8*)(wp + (size_t)((h * 8 + n) * 16) * K2 + (kk + 8) * 32);
#pragma unroll
      for (int n = 0; n < 8; ++n)
        acc[h * 8 + n] = __builtin_amdgcn_mfma_f32_16x16x32_bf16(
            af, bf[n], acc[h * 8 + n], 0, 0, 0);
    }
  }

  // ---- epilogue: bias + LN + GELU + residual, all in-wave ----
  // C/D frag layout: value (n, r) lives at row = q*4 + r, col = n*16 + l15.
  float bv[16], gv[16], bev[16];
#pragma unroll
  for (int n = 0; n < 16; ++n) {
    bv[n]  = biasf[n * 16 + l15];
    gv[n]  = gamma[n * 16 + l15];
    bev[n] = beta [n * 16 + l15];
  }

#pragma unroll
  for (int r = 0; r < 4; ++r) {
    float a = 0.f, b2s = 0.f;
#pragma unroll
    for (int n = 0; n < 16; ++n) {
      const float v = acc[n][r] + bv[n];
      acc[n][r] = v;
      a += v; b2s += v * v;
    }
#pragma unroll
    for (int d = 1; d < 16; d <<= 1) {
      a   += __shfl_xor(a, d, 64);
      b2s += __shfl_xor(b2s, d, 64);
    }
    const float mu   = a * (1.0f / 256.0f);
    const float var  = b2s * (1.0f / 256.0f) - mu * mu;
    const float rstd = rsqrtf(var + 1e-5f);

    const size_t ro = ((size_t)row0 + wave * 16 + q * 4 + r) * H + l15;
    const float* __restrict__ cr = cemb + ro;
    float* __restrict__ orow = out + ro;

    float res[16];
#pragma unroll
    for (int n = 0; n < 16; ++n) res[n] = cr[n * 16];
#pragma unroll
    for (int n = 0; n < 16; ++n) {
      const float x = (acc[n][r] - mu) * rstd;
      const float y = x * gv[n] + bev[n];
      const float g = 0.5f * y * (1.0f + erff(y * 0.70710678118654752f));
      orow[n * 16] = res[n] + g;
    }
  }
}

extern "C" void kernel_launch(void* const* d_in, const int* in_sizes, int n_in,
                              void* d_out, int out_size, void* d_ws, size_t ws_size,
                              hipStream_t stream) {
  const float* cemb  = (const float*)d_in[0];
  const int*   tal   = (const int*)d_in[1];
  const float* dec   = (const float*)d_in[2];
  const float* W1    = (const float*)d_in[3];
  const float* b1    = (const float*)d_in[4];
  const float* W2    = (const float*)d_in[5];
  const float* b2    = (const float*)d_in[6];
  const float* gamma = (const float*)d_in[7];
  const float* beta  = (const float*)d_in[8];
  float* out = (float*)d_out;

  unsigned short* wft = (unsigned short*)d_ws;
  float* biasf = (float*)((char*)d_ws + (size_t)K2 * H * sizeof(unsigned short));

  const int rows = in_sizes[0] / H;   // 131072

  hipLaunchKernelGGL(fuse_weights, dim3(33), dim3(256), 0, stream,
                     W1, W2, b1, b2, wft, biasf);
  hipLaunchKernelGGL(syl_main, dim3(rows / BM), dim3(NTHR), 0, stream,
                     cemb, tal, dec, wft, biasf, gamma, beta, out);
}

// Round 5
// 407.481 us; speedup vs baseline: 1.2376x; 1.2376x over previous
//
#include <hip/hip_runtime.h>
#include <hip/hip_bf16.h>
#include <math.h>
#include <stdint.h>

#define H     256
#define K2    512
#define SDEC  2048
#define LCSH  14
#define BM    64
#define NTHR  256

typedef __attribute__((ext_vector_type(8))) short  short8;
typedef __attribute__((ext_vector_type(4))) float  f32x4;

__device__ __forceinline__ unsigned short f2bf(float f) {
  union { float f; unsigned int u; } c; c.f = f;
  unsigned int u = c.u;
  unsigned int r = u + 0x7fffu + ((u >> 16) & 1u);   // RNE
  return (unsigned short)(r >> 16);
}

// Blocks 0..31: fused weight tiles, written in MFMA B-FRAGMENT ORDER:
//   wft[((n16*16 + kk)*4 + q)*16*8 + l15*8 + e]  (short index)
// i.e. frag (n16,kk) is 64 lanes x short8, lane-contiguous -> syl_main's
// B loads are single coalesced 1KB reads (R4's l15*K2 stride-1KB pattern
// cost ~64 L1 line-touches per load and serialized the kernel).
// Block 32: fused bias (biasf = b2 + b1*W2_bot).
__global__ __launch_bounds__(256) void fuse_weights(
    const float* __restrict__ W1, const float* __restrict__ W2,
    const float* __restrict__ b1, const float* __restrict__ b2,
    unsigned short* __restrict__ wft, float* __restrict__ biasf) {
  if (blockIdx.x == 32) {
    const int n = threadIdx.x;
    float a0 = b2[n], a1 = 0.f, a2 = 0.f, a3 = 0.f;
#pragma unroll 4
    for (int j = 0; j < H; j += 4) {
      a0 += b1[j + 0] * W2[(size_t)(H + j + 0) * H + n];
      a1 += b1[j + 1] * W2[(size_t)(H + j + 1) * H + n];
      a2 += b1[j + 2] * W2[(size_t)(H + j + 2) * H + n];
      a3 += b1[j + 3] * W2[(size_t)(H + j + 3) * H + n];
    }
    biasf[n] = (a0 + a1) + (a2 + a3);
    return;
  }

  __shared__ float As[64][65];
  __shared__ float Bs[64][65];
  const int t  = threadIdx.x;
  const int k0 = (blockIdx.x >> 2) * 64;
  const int n0 = (blockIdx.x & 3) * 64;
  const int lr = t >> 2;
  const int ls = t & 3;
  const int tk = t >> 4;
  const int tn = t & 15;

  float acc[4][4];
#pragma unroll
  for (int i = 0; i < 4; ++i)
#pragma unroll
    for (int c = 0; c < 4; ++c) acc[i][c] = 0.0f;

  for (int jt = 0; jt < 4; ++jt) {
    const int j0 = jt * 64;
    __syncthreads();
    const float* a_src = W1 + (size_t)(k0 + lr) * H + j0 + ls * 16;
    const float* b_src = W2 + (size_t)(H + j0 + lr) * H + n0 + ls * 16;
#pragma unroll
    for (int i = 0; i < 16; ++i) {
      As[lr][ls * 16 + i] = a_src[i];
      Bs[lr][ls * 16 + i] = b_src[i];
    }
    __syncthreads();
#pragma unroll 8
    for (int j = 0; j < 64; ++j) {
      float a[4], b[4];
#pragma unroll
      for (int i = 0; i < 4; ++i) a[i] = As[tk * 4 + i][j];
#pragma unroll
      for (int c = 0; c < 4; ++c) b[c] = Bs[j][tn * 4 + c];
#pragma unroll
      for (int i = 0; i < 4; ++i)
#pragma unroll
        for (int c = 0; c < 4; ++c) acc[i][c] += a[i] * b[c];
    }
  }

#pragma unroll
  for (int i = 0; i < 4; ++i) {
    const int k  = k0 + tk * 4 + i;
    const int kk = k >> 5;
    const int qv = (k >> 3) & 3;
    const int e  = k & 7;
#pragma unroll
    for (int c = 0; c < 4; ++c) {
      const int n = n0 + tn * 4 + c;
      float v = acc[i][c];
      if (k < H) v += W2[(size_t)k * H + n];
      const int n16 = n >> 4;
      const int l15 = n & 15;
      wft[(size_t)(n16 * 16 + kk) * 512 + (qv * 16 + l15) * 8 + e] = f2bf(v);
    }
  }
}

// R5: R4's barrier-free m-split structure (verified correct) + fragment-
// ordered wft so every B load is one coalesced 1KB L1-hot read.
__global__ __launch_bounds__(NTHR, 3) void syl_main(
    const float* __restrict__ cemb, const int* __restrict__ tal,
    const float* __restrict__ dec, const unsigned short* __restrict__ wft,
    const float* __restrict__ biasf, const float* __restrict__ gamma,
    const float* __restrict__ beta, float* __restrict__ out) {

  const int t    = threadIdx.x;
  const int wave = t >> 6;
  const int lane = t & 63;
  const int q    = lane >> 4;
  const int l15  = lane & 15;

  // XCD-chunked swizzle: one batch per XCD -> its 2 MB dec slice stays in
  // that XCD's L2 for the gather.
  const int nwg  = gridDim.x;
  const int bid  = ((nwg & 7) == 0)
                     ? (int)((blockIdx.x & 7) * (nwg >> 3) + (blockIdx.x >> 3))
                     : (int)blockIdx.x;
  const int row0 = bid * BM;
  const int bidx = row0 >> LCSH;

  // this lane's A row (for operand loads)
  const int arow = row0 + wave * 16 + l15;
  int ix = tal[arow];
  const float msk = (ix < 0) ? 0.0f : 1.0f;
  ix = ix < 0 ? 0 : (ix >= SDEC ? SDEC - 1 : ix);

  const float* __restrict__ ap = cemb + (size_t)arow * H + q * 8;
  const float* __restrict__ dp = dec + ((size_t)bidx * SDEC + ix) * H + q * 8;
  const unsigned short* __restrict__ wp = wft + (size_t)lane * 8;

  f32x4 acc[16];
#pragma unroll
  for (int n = 0; n < 16; ++n) acc[n] = (f32x4){0.f, 0.f, 0.f, 0.f};

  // ---- K-loop, char half (k = 0..255), kk steps of 32 ----
#pragma unroll 2
  for (int kk = 0; kk < 8; ++kk) {
    const float4 a0 = *(const float4*)(ap + kk * 32);
    const float4 a1 = *(const float4*)(ap + kk * 32 + 4);
    unsigned short hb[8];
    hb[0] = f2bf(a0.x); hb[1] = f2bf(a0.y); hb[2] = f2bf(a0.z); hb[3] = f2bf(a0.w);
    hb[4] = f2bf(a1.x); hb[5] = f2bf(a1.y); hb[6] = f2bf(a1.z); hb[7] = f2bf(a1.w);
    const short8 af = *(const short8*)hb;
#pragma unroll
    for (int h = 0; h < 2; ++h) {
      short8 bf[8];
#pragma unroll
      for (int n = 0; n < 8; ++n)
        bf[n] = *(const short8*)(wp + (size_t)((h * 8 + n) * 16 + kk) * 512);
#pragma unroll
      for (int n = 0; n < 8; ++n)
        acc[h * 8 + n] = __builtin_amdgcn_mfma_f32_16x16x32_bf16(
            af, bf[n], acc[h * 8 + n], 0, 0, 0);
    }
  }

  // ---- K-loop, gathered-decoder half (k = 256..511) ----
#pragma unroll 2
  for (int kk = 0; kk < 8; ++kk) {
    float4 a0 = *(const float4*)(dp + kk * 32);
    float4 a1 = *(const float4*)(dp + kk * 32 + 4);
    a0.x *= msk; a0.y *= msk; a0.z *= msk; a0.w *= msk;
    a1.x *= msk; a1.y *= msk; a1.z *= msk; a1.w *= msk;
    unsigned short hb[8];
    hb[0] = f2bf(a0.x); hb[1] = f2bf(a0.y); hb[2] = f2bf(a0.z); hb[3] = f2bf(a0.w);
    hb[4] = f2bf(a1.x); hb[5] = f2bf(a1.y); hb[6] = f2bf(a1.z); hb[7] = f2bf(a1.w);
    const short8 af = *(const short8*)hb;
#pragma unroll
    for (int h = 0; h < 2; ++h) {
      short8 bf[8];
#pragma unroll
      for (int n = 0; n < 8; ++n)
        bf[n] = *(const short8*)(wp + (size_t)((h * 8 + n) * 16 + kk + 8) * 512);
#pragma unroll
      for (int n = 0; n < 8; ++n)
        acc[h * 8 + n] = __builtin_amdgcn_mfma_f32_16x16x32_bf16(
            af, bf[n], acc[h * 8 + n], 0, 0, 0);
    }
  }

  // ---- epilogue: bias + LN + GELU + residual, all in-wave ----
  // C/D frag layout: value (n, r) lives at row = q*4 + r, col = n*16 + l15.
  float bv[16], gv[16], bev[16];
#pragma unroll
  for (int n = 0; n < 16; ++n) {
    bv[n]  = biasf[n * 16 + l15];
    gv[n]  = gamma[n * 16 + l15];
    bev[n] = beta [n * 16 + l15];
  }

#pragma unroll
  for (int r = 0; r < 4; ++r) {
    float a = 0.f, b2s = 0.f;
#pragma unroll
    for (int n = 0; n < 16; ++n) {
      const float v = acc[n][r] + bv[n];
      acc[n][r] = v;
      a += v; b2s += v * v;
    }
#pragma unroll
    for (int d = 1; d < 16; d <<= 1) {
      a   += __shfl_xor(a, d, 64);
      b2s += __shfl_xor(b2s, d, 64);
    }
    const float mu   = a * (1.0f / 256.0f);
    const float var  = b2s * (1.0f / 256.0f) - mu * mu;
    const float rstd = rsqrtf(var + 1e-5f);

    const size_t ro = ((size_t)row0 + wave * 16 + q * 4 + r) * H + l15;
    const float* __restrict__ cr = cemb + ro;
    float* __restrict__ orow = out + ro;

    float res[16];
#pragma unroll
    for (int n = 0; n < 16; ++n) res[n] = cr[n * 16];
#pragma unroll
    for (int n = 0; n < 16; ++n) {
      const float x = (acc[n][r] - mu) * rstd;
      const float y = x * gv[n] + bev[n];
      const float g = 0.5f * y * (1.0f + erff(y * 0.70710678118654752f));
      orow[n * 16] = res[n] + g;
    }
  }
}

extern "C" void kernel_launch(void* const* d_in, const int* in_sizes, int n_in,
                              void* d_out, int out_size, void* d_ws, size_t ws_size,
                              hipStream_t stream) {
  const float* cemb  = (const float*)d_in[0];
  const int*   tal   = (const int*)d_in[1];
  const float* dec   = (const float*)d_in[2];
  const float* W1    = (const float*)d_in[3];
  const float* b1    = (const float*)d_in[4];
  const float* W2    = (const float*)d_in[5];
  const float* b2    = (const float*)d_in[6];
  const float* gamma = (const float*)d_in[7];
  const float* beta  = (const float*)d_in[8];
  float* out = (float*)d_out;

  unsigned short* wft = (unsigned short*)d_ws;
  float* biasf = (float*)((char*)d_ws + (size_t)K2 * H * sizeof(unsigned short));

  const int rows = in_sizes[0] / H;   // 131072

  hipLaunchKernelGGL(fuse_weights, dim3(33), dim3(256), 0, stream,
                     W1, W2, b1, b2, wft, biasf);
  hipLaunchKernelGGL(syl_main, dim3(rows / BM), dim3(NTHR), 0, stream,
                     cemb, tal, dec, wft, biasf, gamma, beta, out);
}

// Round 6
// 393.000 us; speedup vs baseline: 1.2833x; 1.0368x over previous
//
#include <hip/hip_runtime.h>
#include <hip/hip_bf16.h>
#include <math.h>
#include <stdint.h>

#define H     256
#define K2    512
#define SDEC  2048
#define LCSH  14
#define BMR   32
#define NTHR  256

typedef __attribute__((ext_vector_type(8))) short  short8;
typedef __attribute__((ext_vector_type(4))) float  f32x4;

__device__ __forceinline__ unsigned short f2bf(float f) {
  union { float f; unsigned int u; } c; c.f = f;
  unsigned int u = c.u;
  unsigned int r = u + 0x7fffu + ((u >> 16) & 1u);   // RNE
  return (unsigned short)(r >> 16);
}

// 8 floats -> 8 bf16 via hardware packed convert (RNE), 4 instrs.
__device__ __forceinline__ short8 pack_bf16x8(float4 a0, float4 a1) {
  union { unsigned int u[4]; short8 s; } r;
  asm("v_cvt_pk_bf16_f32 %0, %1, %2" : "=v"(r.u[0]) : "v"(a0.x), "v"(a0.y));
  asm("v_cvt_pk_bf16_f32 %0, %1, %2" : "=v"(r.u[1]) : "v"(a0.z), "v"(a0.w));
  asm("v_cvt_pk_bf16_f32 %0, %1, %2" : "=v"(r.u[2]) : "v"(a1.x), "v"(a1.y));
  asm("v_cvt_pk_bf16_f32 %0, %1, %2" : "=v"(r.u[3]) : "v"(a1.z), "v"(a1.w));
  return r.s;
}

// GELU with A&S 7.1.25 erf (|eps|<=2.5e-5; output err <=~1e-4, far below
// the bf16-induced 0.03125). ~12 VALU vs erff's ~25-30.
__device__ __forceinline__ float fast_gelu(float y) {
  const float s  = y * 0.70710678118654752f;
  const float ax = fabsf(s);
  const float tt = __builtin_amdgcn_rcpf(1.0f + 0.47047f * ax);
  const float e  = __expf(-ax * ax);
  const float p  = tt * (0.3480242f + tt * (-0.0958798f + tt * 0.7478556f));
  const float er = copysignf(1.0f - p * e, s);
  return 0.5f * y * (1.0f + er);
}

// Blocks 0..31: fused weight tiles, written in MFMA B-FRAGMENT ORDER:
//   wft[(n16*16 + kk)*512 + (q*16 + l15)*8 + e]  (short index)
// so a wave's B-frag load is one coalesced 1KB read.
// Block 32: fused bias (biasf = b2 + b1*W2_bot).
__global__ __launch_bounds__(256) void fuse_weights(
    const float* __restrict__ W1, const float* __restrict__ W2,
    const float* __restrict__ b1, const float* __restrict__ b2,
    unsigned short* __restrict__ wft, float* __restrict__ biasf) {
  if (blockIdx.x == 32) {
    const int n = threadIdx.x;
    float a0 = b2[n], a1 = 0.f, a2 = 0.f, a3 = 0.f;
#pragma unroll 4
    for (int j = 0; j < H; j += 4) {
      a0 += b1[j + 0] * W2[(size_t)(H + j + 0) * H + n];
      a1 += b1[j + 1] * W2[(size_t)(H + j + 1) * H + n];
      a2 += b1[j + 2] * W2[(size_t)(H + j + 2) * H + n];
      a3 += b1[j + 3] * W2[(size_t)(H + j + 3) * H + n];
    }
    biasf[n] = (a0 + a1) + (a2 + a3);
    return;
  }

  __shared__ float As[64][65];
  __shared__ float Bs[64][65];
  const int t  = threadIdx.x;
  const int k0 = (blockIdx.x >> 2) * 64;
  const int n0 = (blockIdx.x & 3) * 64;
  const int lr = t >> 2;
  const int ls = t & 3;
  const int tk = t >> 4;
  const int tn = t & 15;

  float acc[4][4];
#pragma unroll
  for (int i = 0; i < 4; ++i)
#pragma unroll
    for (int c = 0; c < 4; ++c) acc[i][c] = 0.0f;

  for (int jt = 0; jt < 4; ++jt) {
    const int j0 = jt * 64;
    __syncthreads();
    const float* a_src = W1 + (size_t)(k0 + lr) * H + j0 + ls * 16;
    const float* b_src = W2 + (size_t)(H + j0 + lr) * H + n0 + ls * 16;
#pragma unroll
    for (int i = 0; i < 16; ++i) {
      As[lr][ls * 16 + i] = a_src[i];
      Bs[lr][ls * 16 + i] = b_src[i];
    }
    __syncthreads();
#pragma unroll 8
    for (int j = 0; j < 64; ++j) {
      float a[4], b[4];
#pragma unroll
      for (int i = 0; i < 4; ++i) a[i] = As[tk * 4 + i][j];
#pragma unroll
      for (int c = 0; c < 4; ++c) b[c] = Bs[j][tn * 4 + c];
#pragma unroll
      for (int i = 0; i < 4; ++i)
#pragma unroll
        for (int c = 0; c < 4; ++c) acc[i][c] += a[i] * b[c];
    }
  }

#pragma unroll
  for (int i = 0; i < 4; ++i) {
    const int k  = k0 + tk * 4 + i;
    const int kk = k >> 5;
    const int qv = (k >> 3) & 3;
    const int e  = k & 7;
#pragma unroll
    for (int c = 0; c < 4; ++c) {
      const int n = n0 + tn * 4 + c;
      float v = acc[i][c];
      if (k < H) v += W2[(size_t)k * H + n];
      const int n16 = n >> 4;
      const int l15 = n & 15;
      wft[(size_t)(n16 * 16 + kk) * 512 + (qv * 16 + l15) * 8 + e] = f2bf(v);
    }
  }
}

// R6: occupancy push. Per-wave tile halved to 16 rows x 128 cols
// (acc 64 -> 32 VGPRs; ~140 -> ~95 total regs -> 4+ waves/SIMD), block =
// 32 rows with col-split wave pairs. K-loop stays barrier-free; LN stats
// need ONE barrier to combine col-halves via 512 B LDS. cvt_pk for A
// conversion; fast erf for GELU (epilogue was the biggest VALU block).
__global__ __launch_bounds__(NTHR, 4) void syl_main(
    const float* __restrict__ cemb, const int* __restrict__ tal,
    const float* __restrict__ dec, const unsigned short* __restrict__ wft,
    const float* __restrict__ biasf, const float* __restrict__ gamma,
    const float* __restrict__ beta, float* __restrict__ out) {

  __shared__ float st[4][16][2];

  const int t    = threadIdx.x;
  const int wave = t >> 6;
  const int lane = t & 63;
  const int q    = lane >> 4;
  const int l15  = lane & 15;
  const int rw   = wave >> 1;   // row-group (0: rows 0-15, 1: rows 16-31)
  const int ch   = wave & 1;    // col-half (0: cols 0-127, 1: cols 128-255)

  // XCD-chunked swizzle: 4096 blocks = 8 batches x 512 -> one batch per XCD.
  const int nwg  = gridDim.x;
  const int bid  = ((nwg & 7) == 0)
                     ? (int)((blockIdx.x & 7) * (nwg >> 3) + (blockIdx.x >> 3))
                     : (int)blockIdx.x;
  const int row0 = bid * BMR;
  const int bidx = row0 >> LCSH;

  const int arow = row0 + rw * 16 + l15;
  int ix = tal[arow];
  const float msk = (ix < 0) ? 0.0f : 1.0f;
  ix = ix < 0 ? 0 : (ix >= SDEC ? SDEC - 1 : ix);

  const float* __restrict__ ap = cemb + (size_t)arow * H + q * 8;
  const float* __restrict__ dp = dec + ((size_t)bidx * SDEC + ix) * H + q * 8;
  // this wave's B frags: n16 = ch*8 + n
  const unsigned short* __restrict__ wp =
      wft + (size_t)(ch * 8 * 16) * 512 + (size_t)lane * 8;

  f32x4 acc[8];
#pragma unroll
  for (int n = 0; n < 8; ++n) acc[n] = (f32x4){0.f, 0.f, 0.f, 0.f};

  // ---- K-loop, char half (k = 0..255) ----
#pragma unroll 2
  for (int kk = 0; kk < 8; ++kk) {
    const float4 a0 = *(const float4*)(ap + kk * 32);
    const float4 a1 = *(const float4*)(ap + kk * 32 + 4);
    const short8 af = pack_bf16x8(a0, a1);
    short8 bf[8];
#pragma unroll
    for (int n = 0; n < 8; ++n)
      bf[n] = *(const short8*)(wp + (size_t)(n * 16 + kk) * 512);
#pragma unroll
    for (int n = 0; n < 8; ++n)
      acc[n] = __builtin_amdgcn_mfma_f32_16x16x32_bf16(af, bf[n], acc[n], 0, 0, 0);
  }

  // ---- K-loop, gathered-decoder half (k = 256..511) ----
#pragma unroll 2
  for (int kk = 0; kk < 8; ++kk) {
    float4 a0 = *(const float4*)(dp + kk * 32);
    float4 a1 = *(const float4*)(dp + kk * 32 + 4);
    a0.x *= msk; a0.y *= msk; a0.z *= msk; a0.w *= msk;
    a1.x *= msk; a1.y *= msk; a1.z *= msk; a1.w *= msk;
    const short8 af = pack_bf16x8(a0, a1);
    short8 bf[8];
#pragma unroll
    for (int n = 0; n < 8; ++n)
      bf[n] = *(const short8*)(wp + (size_t)(n * 16 + kk + 8) * 512);
#pragma unroll
    for (int n = 0; n < 8; ++n)
      acc[n] = __builtin_amdgcn_mfma_f32_16x16x32_bf16(af, bf[n], acc[n], 0, 0, 0);
  }

  // ---- epilogue ----
  // C/D frag: value (n, r) = row q*4 + r (in wave's 16-row group),
  //           col ch*128 + n*16 + l15.
  float bv[8], gv[8], bev[8];
#pragma unroll
  for (int n = 0; n < 8; ++n) {
    const int col = ch * 128 + n * 16 + l15;
    bv[n]  = biasf[col];
    gv[n]  = gamma[col];
    bev[n] = beta [col];
  }

  // partial LN stats over this wave's 128 cols
#pragma unroll
  for (int r = 0; r < 4; ++r) {
    float a = 0.f, b2s = 0.f;
#pragma unroll
    for (int n = 0; n < 8; ++n) {
      const float v = acc[n][r] + bv[n];
      acc[n][r] = v;
      a += v; b2s += v * v;
    }
#pragma unroll
    for (int d = 1; d < 16; d <<= 1) {
      a   += __shfl_xor(a, d, 64);
      b2s += __shfl_xor(b2s, d, 64);
    }
    if (l15 == 0) {
      st[wave][q * 4 + r][0] = a;
      st[wave][q * 4 + r][1] = b2s;
    }
  }
  __syncthreads();   // the only block-wide barrier

#pragma unroll
  for (int r = 0; r < 4; ++r) {
    const int row = q * 4 + r;
    const float a   = st[wave][row][0] + st[wave ^ 1][row][0];
    const float b2s = st[wave][row][1] + st[wave ^ 1][row][1];
    const float mu   = a * (1.0f / 256.0f);
    const float var  = b2s * (1.0f / 256.0f) - mu * mu;
    const float rstd = rsqrtf(var + 1e-5f);

    const size_t ro = ((size_t)row0 + rw * 16 + row) * H + ch * 128 + l15;
    const float* __restrict__ cr = cemb + ro;
    float* __restrict__ orow = out + ro;

    float res[8];
#pragma unroll
    for (int n = 0; n < 8; ++n) res[n] = cr[n * 16];
#pragma unroll
    for (int n = 0; n < 8; ++n) {
      const float x = (acc[n][r] - mu) * rstd;
      const float y = x * gv[n] + bev[n];
      orow[n * 16] = res[n] + fast_gelu(y);
    }
  }
}

extern "C" void kernel_launch(void* const* d_in, const int* in_sizes, int n_in,
                              void* d_out, int out_size, void* d_ws, size_t ws_size,
                              hipStream_t stream) {
  const float* cemb  = (const float*)d_in[0];
  const int*   tal   = (const int*)d_in[1];
  const float* dec   = (const float*)d_in[2];
  const float* W1    = (const float*)d_in[3];
  const float* b1    = (const float*)d_in[4];
  const float* W2    = (const float*)d_in[5];
  const float* b2    = (const float*)d_in[6];
  const float* gamma = (const float*)d_in[7];
  const float* beta  = (const float*)d_in[8];
  float* out = (float*)d_out;

  unsigned short* wft = (unsigned short*)d_ws;
  float* biasf = (float*)((char*)d_ws + (size_t)K2 * H * sizeof(unsigned short));

  const int rows = in_sizes[0] / H;   // 131072

  hipLaunchKernelGGL(fuse_weights, dim3(33), dim3(256), 0, stream,
                     W1, W2, b1, b2, wft, biasf);
  hipLaunchKernelGGL(syl_main, dim3(rows / BMR), dim3(NTHR), 0, stream,
                     cemb, tal, dec, wft, biasf, gamma, beta, out);
}